// Round 12
// baseline (243.820 us; speedup 1.0000x reference)
//
#include <hip/hip_runtime.h>
#include <hip/hip_fp16.h>
#include <math.h>

#define NO 50000
#define NR 2000
#define NE 600000
#define D  128
#define NEG_SLOPE 0.2f
#define CAP 448    // per-rider edges cached in LDS (mean 300, max ~370)
#define SLOT 512   // fixed capacity per rider segment
#define NB 256     // sort chunk blocks
#define CH ((NE + NB - 1) / NB)   // 2344 edges per chunk

// ---------------------------------------------------------------------------
__global__ void precompute_wv(const float* __restrict__ Ws1, const float* __restrict__ as1,
                              const float* __restrict__ Wd1, const float* __restrict__ ad1,
                              const float* __restrict__ Ws2, const float* __restrict__ as2,
                              const float* __restrict__ Wd2, const float* __restrict__ ad2,
                              float* __restrict__ wsv1, float* __restrict__ wdv1,
                              float* __restrict__ wsv2, float* __restrict__ wdv2) {
    int k = threadIdx.x;
    float s1 = 0.f, d1 = 0.f, s2 = 0.f, d2 = 0.f;
    for (int j = 0; j < D; ++j) {
        s1 += Ws1[k * D + j] * as1[j];
        d1 += Wd1[k * D + j] * ad1[j];
        s2 += Ws2[k * D + j] * as2[j];
        d2 += Wd2[k * D + j] * ad2[j];
    }
    wsv1[k] = s1; wdv1[k] = d1; wsv2[k] = s2; wdv2[k] = d2;
}

// ---------------------------------------------------------------------------
// Fused per-order prep (alphas + fp16 convert) and per-rider alpha_d1.
__global__ void node_prep(const float* __restrict__ x, const float* __restrict__ xr,
                          const float* __restrict__ wsv1, const float* __restrict__ wsv2,
                          const float* __restrict__ wdv1,
                          float* __restrict__ as1o, float* __restrict__ as2o,
                          float* __restrict__ ad1r, __half* __restrict__ x16) {
    int lane = threadIdx.x & 63;
    if (blockIdx.x < NO / 4) {
        int row = blockIdx.x * 4 + (threadIdx.x >> 6);
        float2 xv = ((const float2*)(x + (size_t)row * D))[lane];
        float2 w1 = ((const float2*)wsv1)[lane];
        float2 w2 = ((const float2*)wsv2)[lane];
        float rx0 = fmaxf(xv.x, 0.f), rx1 = fmaxf(xv.y, 0.f);
        ((__half2*)(x16 + (size_t)row * D))[lane] = __floats2half2_rn(xv.x, xv.y);
        float a1 = xv.x * w1.x + xv.y * w1.y;
        float a2 = rx0 * w2.x + rx1 * w2.y;
        for (int off = 32; off; off >>= 1) {
            a1 += __shfl_down(a1, off);
            a2 += __shfl_down(a2, off);
        }
        if (lane == 0) { as1o[row] = a1; as2o[row] = a2; }
    } else {
        int row = (blockIdx.x - NO / 4) * 4 + (threadIdx.x >> 6);
        float2 xv = ((const float2*)(xr + (size_t)row * D))[lane];
        float2 w1 = ((const float2*)wdv1)[lane];
        float a = xv.x * w1.x + xv.y * w1.y;
        for (int off = 32; off; off >>= 1) a += __shfl_down(a, off);
        if (lane == 0) ad1r[row] = a;
    }
}

// ---------------------------------------------------------------------------
// counting sort into fixed-capacity segments (starts[r] == r*SLOT implicitly)
// blockHist layout: [b * NR + r]

__global__ void blockhist_kernel(const int* __restrict__ ri, int* __restrict__ blockHist) {
    __shared__ int h[NR];
    int b = blockIdx.x, t = threadIdx.x;
    for (int i = t; i < NR; i += 256) h[i] = 0;
    __syncthreads();
    int lo = b * CH;
    int hi = lo + CH; if (hi > NE) hi = NE;
    for (int i = lo + t; i < hi; i += 256) atomicAdd(&h[ri[i]], 1);
    __syncthreads();
    for (int i = t; i < NR; i += 256) blockHist[(size_t)b * NR + i] = h[i];
}

// one wave per rider: shuffle-scan across the 256 chunk counts (4 per lane)
__global__ void rowscan_kernel(int* __restrict__ blockHist, int* __restrict__ total) {
    int lane = threadIdx.x & 63;
    int r = blockIdx.x * 4 + (threadIdx.x >> 6);
    if (r >= NR) return;
    int b0 = lane * 4;
    int v0 = blockHist[(size_t)(b0 + 0) * NR + r];
    int v1 = blockHist[(size_t)(b0 + 1) * NR + r];
    int v2 = blockHist[(size_t)(b0 + 2) * NR + r];
    int v3 = blockHist[(size_t)(b0 + 3) * NR + r];
    int s = v0 + v1 + v2 + v3;
    int incl = s;
    for (int off = 1; off < 64; off <<= 1) {
        int u = __shfl_up(incl, off);
        if (lane >= off) incl += u;
    }
    int base = incl - s;  // exclusive across lanes
    blockHist[(size_t)(b0 + 0) * NR + r] = base;
    blockHist[(size_t)(b0 + 1) * NR + r] = base + v0;
    blockHist[(size_t)(b0 + 2) * NR + r] = base + v0 + v1;
    blockHist[(size_t)(b0 + 3) * NR + r] = base + v0 + v1 + v2;
    int tot = __shfl(incl, 63);
    if (lane == 0) total[r] = tot;
}

__global__ void scatter_kernel(const int* __restrict__ oi, const int* __restrict__ ri,
                               const int* __restrict__ blockHist,
                               int* __restrict__ sOrd, int* __restrict__ sEid) {
    __shared__ int h[NR];
    int b = blockIdx.x, t = threadIdx.x;
    for (int i = t; i < NR; i += 256) h[i] = 0;
    __syncthreads();
    int lo = b * CH;
    int hi = lo + CH; if (hi > NE) hi = NE;
    for (int i = lo + t; i < hi; i += 256) {
        int r = ri[i];
        int rank = atomicAdd(&h[r], 1);
        int pos = r * SLOT + blockHist[(size_t)b * NR + r] + rank;
        sOrd[pos] = oi[i];
        sEid[pos] = i;
    }
}

// ---------------------------------------------------------------------------
// Layer 1: softmax (no max-sub; logits bounded) + fp16 gather-sum + fused
// GEMM epilogue ad2r = relu(t1@Ws1+b1)·wdv2.  4 independent loads in flight.
__global__ void __launch_bounds__(256)
rider_agg1(const __half* __restrict__ x16, const float* __restrict__ as_o,
           const float* __restrict__ ad_r,
           const int* __restrict__ cnt, const int* __restrict__ sOrd,
           const float* __restrict__ W, const float* __restrict__ bias,
           const float* __restrict__ wdv2, float* __restrict__ ad2r) {
    __shared__ float eL[CAP];
    __shared__ int   sO[CAP];
    __shared__ float red[256];
    __shared__ float red8[256][9];   // +1 pad breaks stride-8 bank conflicts
    __shared__ float tl[D];
    int r = blockIdx.x, t = threadIdx.x;
    int base = r * SLOT, n = cnt[r];
    float ad = ad_r[r];
    int grp = t >> 4, lh = t & 15;

    // pass 0: exp(leaky_relu(logit)) + sum
    float ls = 0.f;
    for (int i = t; i < n; i += 256) {
        int o = sOrd[base + i];
        float e = as_o[o] + ad;
        e = (e > 0.f) ? e : NEG_SLOPE * e;
        float ex = __expf(e);
        if (i < CAP) { eL[i] = ex; sO[i] = o; }
        ls += ex;
    }
    red[t] = ls;
    __syncthreads();
    for (int off = 128; off; off >>= 1) {
        if (t < off) red[t] += red[t + off];
        __syncthreads();
    }
    float inv = 1.f / (red[0] + 1e-16f);
    __syncthreads();

    // pass 1: fp16 gather, 16 groups x 16 lanes, 8 d's per lane, 4-deep unroll
    float acc[8];
#pragma unroll
    for (int k = 0; k < 8; ++k) acc[k] = 0.f;
    if (n <= CAP) {
        int i = grp;
        for (; i + 48 < n; i += 64) {
            float a0 = eL[i], a1 = eL[i + 16], a2 = eL[i + 32], a3 = eL[i + 48];
            uint4 h0 = ((const uint4*)(x16 + (size_t)sO[i]      * D))[lh];
            uint4 h1 = ((const uint4*)(x16 + (size_t)sO[i + 16] * D))[lh];
            uint4 h2 = ((const uint4*)(x16 + (size_t)sO[i + 32] * D))[lh];
            uint4 h3 = ((const uint4*)(x16 + (size_t)sO[i + 48] * D))[lh];
            const __half2* p0 = (const __half2*)&h0;
            const __half2* p1 = (const __half2*)&h1;
            const __half2* p2 = (const __half2*)&h2;
            const __half2* p3 = (const __half2*)&h3;
#pragma unroll
            for (int q = 0; q < 4; ++q) {
                float2 f0 = __half22float2(p0[q]);
                float2 f1 = __half22float2(p1[q]);
                float2 f2 = __half22float2(p2[q]);
                float2 f3 = __half22float2(p3[q]);
                acc[2 * q]     += a0 * f0.x + a1 * f1.x + a2 * f2.x + a3 * f3.x;
                acc[2 * q + 1] += a0 * f0.y + a1 * f1.y + a2 * f2.y + a3 * f3.y;
            }
        }
        for (; i + 16 < n; i += 32) {
            float a0 = eL[i], a1 = eL[i + 16];
            uint4 h0 = ((const uint4*)(x16 + (size_t)sO[i]      * D))[lh];
            uint4 h1 = ((const uint4*)(x16 + (size_t)sO[i + 16] * D))[lh];
            const __half2* p0 = (const __half2*)&h0;
            const __half2* p1 = (const __half2*)&h1;
#pragma unroll
            for (int q = 0; q < 4; ++q) {
                float2 f0 = __half22float2(p0[q]);
                float2 f1 = __half22float2(p1[q]);
                acc[2 * q]     += a0 * f0.x + a1 * f1.x;
                acc[2 * q + 1] += a0 * f0.y + a1 * f1.y;
            }
        }
        if (i < n) {
            float a0 = eL[i];
            uint4 h0 = ((const uint4*)(x16 + (size_t)sO[i] * D))[lh];
            const __half2* p0 = (const __half2*)&h0;
#pragma unroll
            for (int q = 0; q < 4; ++q) {
                float2 f0 = __half22float2(p0[q]);
                acc[2 * q]     += a0 * f0.x;
                acc[2 * q + 1] += a0 * f0.y;
            }
        }
    } else {
        for (int i = grp; i < n; i += 16) {
            float a0; int o;
            if (i < CAP) { a0 = eL[i]; o = sO[i]; }
            else {
                o = sOrd[base + i];
                float e = as_o[o] + ad;
                e = (e > 0.f) ? e : NEG_SLOPE * e;
                a0 = __expf(e);
            }
            uint4 h0 = ((const uint4*)(x16 + (size_t)o * D))[lh];
            const __half2* p0 = (const __half2*)&h0;
#pragma unroll
            for (int q = 0; q < 4; ++q) {
                float2 f0 = __half22float2(p0[q]);
                acc[2 * q]     += a0 * f0.x;
                acc[2 * q + 1] += a0 * f0.y;
            }
        }
    }
#pragma unroll
    for (int k = 0; k < 8; ++k) red8[t][k] = acc[k];
    __syncthreads();
    if (t < D) {
        int lh2 = t >> 3, k = t & 7;
        float s = 0.f;
        for (int g = 0; g < 16; ++g) s += red8[g * 16 + lh2][k];
        tl[t] = s * inv;
    }
    __syncthreads();

    // fused GEMM epilogue -> scalar ad2
    int d = t & 127, h = t >> 7;
    float a2 = 0.f;
    for (int k = h * 64; k < h * 64 + 64; ++k) a2 += tl[k] * W[k * D + d];
    red[t] = a2;
    __syncthreads();
    if (t < 128) red[t] = fmaxf(red[t] + red[t + 128] + bias[t], 0.f) * wdv2[t];
    __syncthreads();
    for (int off = 64; off; off >>= 1) {
        if (t < off) red[t] += red[t + off];
        __syncthreads();
    }
    if (t == 0) ad2r[r] = red[0];
}

// ---------------------------------------------------------------------------
// Layer 2 + scoring, fused (NO LDS row cache — rely on per-XCD L2 for the
// re-gather; R7 showed the 48 KB cache kills occupancy):
//   softmax2 + gather-sum(relu x) -> t2 -> GEMM(Ws2) -> r2 (LDS)
//   then re-gather rows (L2-hot) and out[eid] = sigmoid(relu(x[o])·r2).
__global__ void __launch_bounds__(256)
agg2_score(const __half* __restrict__ x16, const float* __restrict__ as_o,
           const float* __restrict__ ad_r,
           const int* __restrict__ cnt,
           const int* __restrict__ sOrd, const int* __restrict__ sEid,
           const float* __restrict__ W, const float* __restrict__ bias,
           float* __restrict__ out) {
    __shared__ float eL[CAP];
    __shared__ int   sO[CAP];
    __shared__ int   sE[CAP];
    __shared__ float red[256];
    __shared__ float red8[256][9];
    __shared__ float tl[D];
    __shared__ float r2L[D];
    int r = blockIdx.x, t = threadIdx.x;
    int base = r * SLOT, n = cnt[r];
    float ad = ad_r[r];
    int grp = t >> 4, lh = t & 15;

    // pass 0: exp(leaky_relu(logit)) + sum; cache o, eid
    float ls = 0.f;
    for (int i = t; i < n; i += 256) {
        int o = sOrd[base + i];
        float e = as_o[o] + ad;
        e = (e > 0.f) ? e : NEG_SLOPE * e;
        float ex = __expf(e);
        if (i < CAP) { eL[i] = ex; sO[i] = o; sE[i] = sEid[base + i]; }
        ls += ex;
    }
    red[t] = ls;
    __syncthreads();
    for (int off = 128; off; off >>= 1) {
        if (t < off) red[t] += red[t + off];
        __syncthreads();
    }
    float inv = 1.f / (red[0] + 1e-16f);
    __syncthreads();

    // pass 1: gather, t2 = sum exp2 * relu(x); 2-deep unroll (VGPR headroom)
    float acc[8];
#pragma unroll
    for (int k = 0; k < 8; ++k) acc[k] = 0.f;
    if (n <= CAP) {
        int i = grp;
        for (; i + 16 < n; i += 32) {
            float a0 = eL[i], a1 = eL[i + 16];
            uint4 h0 = ((const uint4*)(x16 + (size_t)sO[i]      * D))[lh];
            uint4 h1 = ((const uint4*)(x16 + (size_t)sO[i + 16] * D))[lh];
            const __half2* p0 = (const __half2*)&h0;
            const __half2* p1 = (const __half2*)&h1;
#pragma unroll
            for (int q = 0; q < 4; ++q) {
                float2 f0 = __half22float2(p0[q]);
                float2 f1 = __half22float2(p1[q]);
                acc[2 * q]     += a0 * fmaxf(f0.x, 0.f) + a1 * fmaxf(f1.x, 0.f);
                acc[2 * q + 1] += a0 * fmaxf(f0.y, 0.f) + a1 * fmaxf(f1.y, 0.f);
            }
        }
        if (i < n) {
            float a0 = eL[i];
            uint4 h0 = ((const uint4*)(x16 + (size_t)sO[i] * D))[lh];
            const __half2* p0 = (const __half2*)&h0;
#pragma unroll
            for (int q = 0; q < 4; ++q) {
                float2 f0 = __half22float2(p0[q]);
                acc[2 * q]     += a0 * fmaxf(f0.x, 0.f);
                acc[2 * q + 1] += a0 * fmaxf(f0.y, 0.f);
            }
        }
    } else {
        for (int i = grp; i < n; i += 16) {
            float a0; int o;
            if (i < CAP) { a0 = eL[i]; o = sO[i]; }
            else {
                o = sOrd[base + i];
                float e = as_o[o] + ad;
                e = (e > 0.f) ? e : NEG_SLOPE * e;
                a0 = __expf(e);
            }
            uint4 h0 = ((const uint4*)(x16 + (size_t)o * D))[lh];
            const __half2* p0 = (const __half2*)&h0;
#pragma unroll
            for (int q = 0; q < 4; ++q) {
                float2 f0 = __half22float2(p0[q]);
                acc[2 * q]     += a0 * fmaxf(f0.x, 0.f);
                acc[2 * q + 1] += a0 * fmaxf(f0.y, 0.f);
            }
        }
    }
#pragma unroll
    for (int k = 0; k < 8; ++k) red8[t][k] = acc[k];
    __syncthreads();
    if (t < D) {
        int lh2 = t >> 3, k = t & 7;
        float s = 0.f;
        for (int g = 0; g < 16; ++g) s += red8[g * 16 + lh2][k];
        tl[t] = s * inv;
    }
    __syncthreads();

    // GEMM2: r2 = t2@Ws2 + b2 (kept in LDS)
    {
        int d = t & 127, h = t >> 7;
        float a = 0.f;
        for (int k = h * 64; k < h * 64 + 64; ++k) a += tl[k] * W[k * D + d];
        red[t] = a;
        __syncthreads();
        if (t < 128) r2L[t] = red[t] + red[t + 128] + bias[t];
        __syncthreads();
    }

    // pass 2: score each edge; rows are L2-hot from pass 1 (same CU/XCD)
    float rv[8];
#pragma unroll
    for (int k = 0; k < 8; ++k) rv[k] = r2L[lh * 8 + k];
    for (int i = grp; i < n; i += 16) {
        int o, eid;
        if (i < CAP) { o = sO[i]; eid = sE[i]; }
        else { o = sOrd[base + i]; eid = sEid[base + i]; }
        uint4 h0 = ((const uint4*)(x16 + (size_t)o * D))[lh];
        const __half2* p0 = (const __half2*)&h0;
        float p = 0.f;
#pragma unroll
        for (int q = 0; q < 4; ++q) {
            float2 f0 = __half22float2(p0[q]);
            p += fmaxf(f0.x, 0.f) * rv[2 * q] + fmaxf(f0.y, 0.f) * rv[2 * q + 1];
        }
        p += __shfl_xor(p, 8);
        p += __shfl_xor(p, 4);
        p += __shfl_xor(p, 2);
        p += __shfl_xor(p, 1);
        if (lh == 0) out[eid] = 1.f / (1.f + __expf(-p));
    }
}

// ---------------------------------------------------------------------------
extern "C" void kernel_launch(void* const* d_in, const int* in_sizes, int n_in,
                              void* d_out, int out_size, void* d_ws, size_t ws_size,
                              hipStream_t stream) {
    const float* x_order = (const float*)d_in[0];
    const float* x_rider = (const float*)d_in[1];
    const int*   oi      = (const int*)d_in[2];
    const int*   ri      = (const int*)d_in[3];
    const float* Ws1 = (const float*)d_in[4];
    const float* Wd1 = (const float*)d_in[5];
    const float* as1 = (const float*)d_in[6];
    const float* ad1 = (const float*)d_in[7];
    const float* b1  = (const float*)d_in[8];
    const float* Ws2 = (const float*)d_in[9];
    const float* Wd2 = (const float*)d_in[10];
    const float* as2 = (const float*)d_in[11];
    const float* ad2 = (const float*)d_in[12];
    const float* b2  = (const float*)d_in[13];
    float* out = (float*)d_out;

    // workspace carve-up (16B-aligned chunks)
    char* w = (char*)d_ws;
    float* wsv1 = (float*)w; w += 512;
    float* wdv1 = (float*)w; w += 512;
    float* wsv2 = (float*)w; w += 512;
    float* wdv2 = (float*)w; w += 512;
    float* as1o = (float*)w; w += (size_t)NO * 4;        // 200 KB
    float* as2o = (float*)w; w += (size_t)NO * 4;
    float* ad1r = (float*)w; w += (size_t)NR * 4;        // 8 KB
    float* ad2r = (float*)w; w += (size_t)NR * 4;
    int* total  = (int*)w;   w += (size_t)NR * 4;
    int* blockHist = (int*)w; w += (size_t)NB * NR * 4;  // 2 MB
    int* sOrd   = (int*)w;   w += (size_t)NR * SLOT * 4; // 4 MB
    int* sEid   = (int*)w;   w += (size_t)NR * SLOT * 4; // 4 MB
    __half* x16 = (__half*)w; w += (size_t)NO * D * 2;   // 12.8 MB

    precompute_wv<<<1, 128, 0, stream>>>(Ws1, as1, Wd1, ad1, Ws2, as2, Wd2, ad2,
                                         wsv1, wdv1, wsv2, wdv2);
    node_prep<<<NO / 4 + NR / 4, 256, 0, stream>>>(x_order, x_rider, wsv1, wsv2, wdv1,
                                                   as1o, as2o, ad1r, x16);

    blockhist_kernel<<<NB, 256, 0, stream>>>(ri, blockHist);
    rowscan_kernel<<<NR / 4, 256, 0, stream>>>(blockHist, total);
    scatter_kernel<<<NB, 256, 0, stream>>>(oi, ri, blockHist, sOrd, sEid);

    rider_agg1<<<NR, 256, 0, stream>>>(x16, as1o, ad1r, total, sOrd,
                                       Ws1, b1, wdv2, ad2r);
    agg2_score<<<NR, 256, 0, stream>>>(x16, as2o, ad2r, total, sOrd, sEid,
                                       Ws2, b2, out);
}

// Round 13
// 236.155 us; speedup vs baseline: 1.0325x; 1.0325x over previous
//
#include <hip/hip_runtime.h>
#include <hip/hip_fp16.h>
#include <math.h>

#define NO 50000
#define NR 2000
#define NE 600000
#define D  128
#define NEG_SLOPE 0.2f
#define HCAP 256   // per-half edges cached in LDS (half of max ~370 => ~190)
#define SLOT 512   // fixed capacity per rider segment
#define NB 256     // sort chunk blocks
#define CH ((NE + NB - 1) / NB)   // 2344 edges per chunk

// ---------------------------------------------------------------------------
__global__ void precompute_wv(const float* __restrict__ Ws1, const float* __restrict__ as1,
                              const float* __restrict__ Wd1, const float* __restrict__ ad1,
                              const float* __restrict__ Ws2, const float* __restrict__ as2,
                              const float* __restrict__ Wd2, const float* __restrict__ ad2,
                              float* __restrict__ wsv1, float* __restrict__ wdv1,
                              float* __restrict__ wsv2, float* __restrict__ wdv2) {
    int k = threadIdx.x;
    float s1 = 0.f, d1 = 0.f, s2 = 0.f, d2 = 0.f;
    for (int j = 0; j < D; ++j) {
        s1 += Ws1[k * D + j] * as1[j];
        d1 += Wd1[k * D + j] * ad1[j];
        s2 += Ws2[k * D + j] * as2[j];
        d2 += Wd2[k * D + j] * ad2[j];
    }
    wsv1[k] = s1; wdv1[k] = d1; wsv2[k] = s2; wdv2[k] = d2;
}

// ---------------------------------------------------------------------------
// Fused per-order prep (alphas + fp16 convert) and per-rider alpha_d1.
__global__ void node_prep(const float* __restrict__ x, const float* __restrict__ xr,
                          const float* __restrict__ wsv1, const float* __restrict__ wsv2,
                          const float* __restrict__ wdv1,
                          float* __restrict__ as1o, float* __restrict__ as2o,
                          float* __restrict__ ad1r, __half* __restrict__ x16) {
    int lane = threadIdx.x & 63;
    if (blockIdx.x < NO / 4) {
        int row = blockIdx.x * 4 + (threadIdx.x >> 6);
        float2 xv = ((const float2*)(x + (size_t)row * D))[lane];
        float2 w1 = ((const float2*)wsv1)[lane];
        float2 w2 = ((const float2*)wsv2)[lane];
        float rx0 = fmaxf(xv.x, 0.f), rx1 = fmaxf(xv.y, 0.f);
        ((__half2*)(x16 + (size_t)row * D))[lane] = __floats2half2_rn(xv.x, xv.y);
        float a1 = xv.x * w1.x + xv.y * w1.y;
        float a2 = rx0 * w2.x + rx1 * w2.y;
        for (int off = 32; off; off >>= 1) {
            a1 += __shfl_down(a1, off);
            a2 += __shfl_down(a2, off);
        }
        if (lane == 0) { as1o[row] = a1; as2o[row] = a2; }
    } else {
        int row = (blockIdx.x - NO / 4) * 4 + (threadIdx.x >> 6);
        float2 xv = ((const float2*)(xr + (size_t)row * D))[lane];
        float2 w1 = ((const float2*)wdv1)[lane];
        float a = xv.x * w1.x + xv.y * w1.y;
        for (int off = 32; off; off >>= 1) a += __shfl_down(a, off);
        if (lane == 0) ad1r[row] = a;
    }
}

// ---------------------------------------------------------------------------
// counting sort into fixed-capacity segments (starts[r] == r*SLOT implicitly)
// blockHist layout: [b * NR + r]

__global__ void blockhist_kernel(const int* __restrict__ ri, int* __restrict__ blockHist) {
    __shared__ int h[NR];
    int b = blockIdx.x, t = threadIdx.x;
    for (int i = t; i < NR; i += 256) h[i] = 0;
    __syncthreads();
    int lo = b * CH;
    int hi = lo + CH; if (hi > NE) hi = NE;
    for (int i = lo + t; i < hi; i += 256) atomicAdd(&h[ri[i]], 1);
    __syncthreads();
    for (int i = t; i < NR; i += 256) blockHist[(size_t)b * NR + i] = h[i];
}

// one wave per rider: shuffle-scan across the 256 chunk counts (4 per lane)
__global__ void rowscan_kernel(int* __restrict__ blockHist, int* __restrict__ total) {
    int lane = threadIdx.x & 63;
    int r = blockIdx.x * 4 + (threadIdx.x >> 6);
    if (r >= NR) return;
    int b0 = lane * 4;
    int v0 = blockHist[(size_t)(b0 + 0) * NR + r];
    int v1 = blockHist[(size_t)(b0 + 1) * NR + r];
    int v2 = blockHist[(size_t)(b0 + 2) * NR + r];
    int v3 = blockHist[(size_t)(b0 + 3) * NR + r];
    int s = v0 + v1 + v2 + v3;
    int incl = s;
    for (int off = 1; off < 64; off <<= 1) {
        int u = __shfl_up(incl, off);
        if (lane >= off) incl += u;
    }
    int base = incl - s;  // exclusive across lanes
    blockHist[(size_t)(b0 + 0) * NR + r] = base;
    blockHist[(size_t)(b0 + 1) * NR + r] = base + v0;
    blockHist[(size_t)(b0 + 2) * NR + r] = base + v0 + v1;
    blockHist[(size_t)(b0 + 3) * NR + r] = base + v0 + v1 + v2;
    int tot = __shfl(incl, 63);
    if (lane == 0) total[r] = tot;
}

__global__ void scatter_kernel(const int* __restrict__ oi, const int* __restrict__ ri,
                               const int* __restrict__ blockHist,
                               int* __restrict__ sOrd) {
    __shared__ int h[NR];
    int b = blockIdx.x, t = threadIdx.x;
    for (int i = t; i < NR; i += 256) h[i] = 0;
    __syncthreads();
    int lo = b * CH;
    int hi = lo + CH; if (hi > NE) hi = NE;
    for (int i = lo + t; i < hi; i += 256) {
        int r = ri[i];
        int rank = atomicAdd(&h[r], 1);
        int pos = r * SLOT + blockHist[(size_t)b * NR + r] + rank;
        sOrd[pos] = oi[i];
    }
}

// ---------------------------------------------------------------------------
// Split-rider partial aggregation: 2 blocks per rider, each handles half the
// edge list.  Emits partial exp-sum ps[b] and unnormalized partial feature
// sum pt[b][128].  L==1: raw x.  L==2: relu(x) inline.
template <int L>
__global__ void __launch_bounds__(256)
agg_part(const __half* __restrict__ x16, const float* __restrict__ as_o,
         const float* __restrict__ ad_r,
         const int* __restrict__ cnt, const int* __restrict__ sOrd,
         float* __restrict__ ps, float* __restrict__ pt) {
    __shared__ float eL[HCAP];
    __shared__ int   sO[HCAP];
    __shared__ float red[256];
    __shared__ float red8[256][9];   // +1 pad breaks stride-8 bank conflicts
    int b = blockIdx.x, t = threadIdx.x;
    int r = b >> 1, half = b & 1;
    int n = cnt[r];
    int m0 = (n + 1) >> 1;
    int beg = r * SLOT + (half ? m0 : 0);
    int m = half ? (n - m0) : m0;
    float ad = ad_r[r];
    int grp = t >> 4, lh = t & 15;

    // pass 0: exp(leaky_relu(logit)) + partial sum
    float ls = 0.f;
    for (int i = t; i < m; i += 256) {
        int o = sOrd[beg + i];
        float e = as_o[o] + ad;
        e = (e > 0.f) ? e : NEG_SLOPE * e;
        float ex = __expf(e);
        if (i < HCAP) { eL[i] = ex; sO[i] = o; }
        ls += ex;
    }
    red[t] = ls;
    __syncthreads();
    for (int off = 128; off; off >>= 1) {
        if (t < off) red[t] += red[t + off];
        __syncthreads();
    }
    if (t == 0) ps[b] = red[0];

    // pass 1: fp16 gather, 16 groups x 16 lanes, 8 d's per lane, 4-deep unroll
    float acc[8];
#pragma unroll
    for (int k = 0; k < 8; ++k) acc[k] = 0.f;
    if (m <= HCAP) {
        int i = grp;
        for (; i + 48 < m; i += 64) {
            float a0 = eL[i], a1 = eL[i + 16], a2 = eL[i + 32], a3 = eL[i + 48];
            uint4 h0 = ((const uint4*)(x16 + (size_t)sO[i]      * D))[lh];
            uint4 h1 = ((const uint4*)(x16 + (size_t)sO[i + 16] * D))[lh];
            uint4 h2 = ((const uint4*)(x16 + (size_t)sO[i + 32] * D))[lh];
            uint4 h3 = ((const uint4*)(x16 + (size_t)sO[i + 48] * D))[lh];
            const __half2* p0 = (const __half2*)&h0;
            const __half2* p1 = (const __half2*)&h1;
            const __half2* p2 = (const __half2*)&h2;
            const __half2* p3 = (const __half2*)&h3;
#pragma unroll
            for (int q = 0; q < 4; ++q) {
                float2 f0 = __half22float2(p0[q]);
                float2 f1 = __half22float2(p1[q]);
                float2 f2 = __half22float2(p2[q]);
                float2 f3 = __half22float2(p3[q]);
                if (L == 2) {
                    f0.x = fmaxf(f0.x, 0.f); f0.y = fmaxf(f0.y, 0.f);
                    f1.x = fmaxf(f1.x, 0.f); f1.y = fmaxf(f1.y, 0.f);
                    f2.x = fmaxf(f2.x, 0.f); f2.y = fmaxf(f2.y, 0.f);
                    f3.x = fmaxf(f3.x, 0.f); f3.y = fmaxf(f3.y, 0.f);
                }
                acc[2 * q]     += a0 * f0.x + a1 * f1.x + a2 * f2.x + a3 * f3.x;
                acc[2 * q + 1] += a0 * f0.y + a1 * f1.y + a2 * f2.y + a3 * f3.y;
            }
        }
        for (; i + 16 < m; i += 32) {
            float a0 = eL[i], a1 = eL[i + 16];
            uint4 h0 = ((const uint4*)(x16 + (size_t)sO[i]      * D))[lh];
            uint4 h1 = ((const uint4*)(x16 + (size_t)sO[i + 16] * D))[lh];
            const __half2* p0 = (const __half2*)&h0;
            const __half2* p1 = (const __half2*)&h1;
#pragma unroll
            for (int q = 0; q < 4; ++q) {
                float2 f0 = __half22float2(p0[q]);
                float2 f1 = __half22float2(p1[q]);
                if (L == 2) {
                    f0.x = fmaxf(f0.x, 0.f); f0.y = fmaxf(f0.y, 0.f);
                    f1.x = fmaxf(f1.x, 0.f); f1.y = fmaxf(f1.y, 0.f);
                }
                acc[2 * q]     += a0 * f0.x + a1 * f1.x;
                acc[2 * q + 1] += a0 * f0.y + a1 * f1.y;
            }
        }
        if (i < m) {
            float a0 = eL[i];
            uint4 h0 = ((const uint4*)(x16 + (size_t)sO[i] * D))[lh];
            const __half2* p0 = (const __half2*)&h0;
#pragma unroll
            for (int q = 0; q < 4; ++q) {
                float2 f0 = __half22float2(p0[q]);
                if (L == 2) { f0.x = fmaxf(f0.x, 0.f); f0.y = fmaxf(f0.y, 0.f); }
                acc[2 * q]     += a0 * f0.x;
                acc[2 * q + 1] += a0 * f0.y;
            }
        }
    } else {
        for (int i = grp; i < m; i += 16) {
            float a0; int o;
            if (i < HCAP) { a0 = eL[i]; o = sO[i]; }
            else {
                o = sOrd[beg + i];
                float e = as_o[o] + ad;
                e = (e > 0.f) ? e : NEG_SLOPE * e;
                a0 = __expf(e);
            }
            uint4 h0 = ((const uint4*)(x16 + (size_t)o * D))[lh];
            const __half2* p0 = (const __half2*)&h0;
#pragma unroll
            for (int q = 0; q < 4; ++q) {
                float2 f0 = __half22float2(p0[q]);
                if (L == 2) { f0.x = fmaxf(f0.x, 0.f); f0.y = fmaxf(f0.y, 0.f); }
                acc[2 * q]     += a0 * f0.x;
                acc[2 * q + 1] += a0 * f0.y;
            }
        }
    }
#pragma unroll
    for (int k = 0; k < 8; ++k) red8[t][k] = acc[k];
    __syncthreads();
    if (t < D) {
        int lh2 = t >> 3, k = t & 7;
        float s = 0.f;
        for (int g = 0; g < 16; ++g) s += red8[g * 16 + lh2][k];
        pt[(size_t)b * D + t] = s;
    }
}

// ---------------------------------------------------------------------------
// Per-rider combine: t = (pt0+pt1)/(ps0+ps1), then 128x128 GEMM epilogue.
// L==1: ad2r = relu(t@Ws1+b1)·wdv2.   L==2: r216 = fp16(t@Ws2+b2).
template <int L>
__global__ void __launch_bounds__(256)
combine(const float* __restrict__ ps, const float* __restrict__ pt,
        const float* __restrict__ W, const float* __restrict__ bias,
        const float* __restrict__ wdv2,
        float* __restrict__ ad2r, __half* __restrict__ r216) {
    __shared__ float tl[D];
    __shared__ float red[256];
    int r = blockIdx.x, t = threadIdx.x;
    if (t < D) {
        float inv = 1.f / (ps[2 * r] + ps[2 * r + 1] + 1e-16f);
        tl[t] = (pt[(size_t)(2 * r) * D + t] + pt[(size_t)(2 * r + 1) * D + t]) * inv;
    }
    __syncthreads();
    int d = t & 127, h = t >> 7;
    float a = 0.f;
    for (int k = h * 64; k < h * 64 + 64; ++k) a += tl[k] * W[k * D + d];
    red[t] = a;
    __syncthreads();
    if (L == 1) {
        if (t < 128) red[t] = fmaxf(red[t] + red[t + 128] + bias[t], 0.f) * wdv2[t];
        __syncthreads();
        for (int off = 64; off; off >>= 1) {
            if (t < off) red[t] += red[t + off];
            __syncthreads();
        }
        if (t == 0) ad2r[r] = red[0];
    } else {
        if (t < 128) r216[(size_t)r * D + t] = __float2half(red[t] + red[t + 128] + bias[t]);
    }
}

// ---------------------------------------------------------------------------
// edge-parallel scoring: 16 lanes per edge, fp16 both sides, relu(x) inline
__global__ void score_edges(const __half* __restrict__ x16, const __half* __restrict__ r216,
                            const int* __restrict__ oi, const int* __restrict__ ri,
                            float* __restrict__ out) {
    int gid = blockIdx.x * blockDim.x + threadIdx.x;
    int e  = gid >> 4;
    int lh = gid & 15;
    if (e >= NE) return;
    int o = oi[e], r = ri[e];
    uint4 hx = ((const uint4*)(x16  + (size_t)o * D))[lh];
    uint4 hr = ((const uint4*)(r216 + (size_t)r * D))[lh];
    float2 a0 = __half22float2(*(const __half2*)&hx.x);
    float2 a1 = __half22float2(*(const __half2*)&hx.y);
    float2 a2 = __half22float2(*(const __half2*)&hx.z);
    float2 a3 = __half22float2(*(const __half2*)&hx.w);
    float2 b0 = __half22float2(*(const __half2*)&hr.x);
    float2 b1 = __half22float2(*(const __half2*)&hr.y);
    float2 b2 = __half22float2(*(const __half2*)&hr.z);
    float2 b3 = __half22float2(*(const __half2*)&hr.w);
    float p = fmaxf(a0.x, 0.f) * b0.x + fmaxf(a0.y, 0.f) * b0.y +
              fmaxf(a1.x, 0.f) * b1.x + fmaxf(a1.y, 0.f) * b1.y +
              fmaxf(a2.x, 0.f) * b2.x + fmaxf(a2.y, 0.f) * b2.y +
              fmaxf(a3.x, 0.f) * b3.x + fmaxf(a3.y, 0.f) * b3.y;
    p += __shfl_xor(p, 8);
    p += __shfl_xor(p, 4);
    p += __shfl_xor(p, 2);
    p += __shfl_xor(p, 1);
    if (lh == 0) out[e] = 1.f / (1.f + __expf(-p));
}

// ---------------------------------------------------------------------------
extern "C" void kernel_launch(void* const* d_in, const int* in_sizes, int n_in,
                              void* d_out, int out_size, void* d_ws, size_t ws_size,
                              hipStream_t stream) {
    const float* x_order = (const float*)d_in[0];
    const float* x_rider = (const float*)d_in[1];
    const int*   oi      = (const int*)d_in[2];
    const int*   ri      = (const int*)d_in[3];
    const float* Ws1 = (const float*)d_in[4];
    const float* Wd1 = (const float*)d_in[5];
    const float* as1 = (const float*)d_in[6];
    const float* ad1 = (const float*)d_in[7];
    const float* b1  = (const float*)d_in[8];
    const float* Ws2 = (const float*)d_in[9];
    const float* Wd2 = (const float*)d_in[10];
    const float* as2 = (const float*)d_in[11];
    const float* ad2 = (const float*)d_in[12];
    const float* b2  = (const float*)d_in[13];
    float* out = (float*)d_out;

    // workspace carve-up (16B-aligned chunks)
    char* w = (char*)d_ws;
    float* wsv1 = (float*)w; w += 512;
    float* wdv1 = (float*)w; w += 512;
    float* wsv2 = (float*)w; w += 512;
    float* wdv2 = (float*)w; w += 512;
    float* as1o = (float*)w; w += (size_t)NO * 4;        // 200 KB
    float* as2o = (float*)w; w += (size_t)NO * 4;
    float* ad1r = (float*)w; w += (size_t)NR * 4;        // 8 KB
    float* ad2r = (float*)w; w += (size_t)NR * 4;
    int* total  = (int*)w;   w += (size_t)NR * 4;
    float* ps   = (float*)w; w += (size_t)2 * NR * 4;    // 16 KB
    int* blockHist = (int*)w; w += (size_t)NB * NR * 4;  // 2 MB
    int* sOrd   = (int*)w;   w += (size_t)NR * SLOT * 4; // 4 MB
    float* pt   = (float*)w; w += (size_t)2 * NR * D * 4;// 2 MB
    __half* x16  = (__half*)w; w += (size_t)NO * D * 2;  // 12.8 MB
    __half* r216 = (__half*)w; w += (size_t)NR * D * 2;  // 512 KB

    precompute_wv<<<1, 128, 0, stream>>>(Ws1, as1, Wd1, ad1, Ws2, as2, Wd2, ad2,
                                         wsv1, wdv1, wsv2, wdv2);
    node_prep<<<NO / 4 + NR / 4, 256, 0, stream>>>(x_order, x_rider, wsv1, wsv2, wdv1,
                                                   as1o, as2o, ad1r, x16);

    blockhist_kernel<<<NB, 256, 0, stream>>>(ri, blockHist);
    rowscan_kernel<<<NR / 4, 256, 0, stream>>>(blockHist, total);
    scatter_kernel<<<NB, 256, 0, stream>>>(oi, ri, blockHist, sOrd);

    agg_part<1><<<2 * NR, 256, 0, stream>>>(x16, as1o, ad1r, total, sOrd, ps, pt);
    combine<1><<<NR, 256, 0, stream>>>(ps, pt, Ws1, b1, wdv2, ad2r, (__half*)0);
    agg_part<2><<<2 * NR, 256, 0, stream>>>(x16, as2o, ad2r, total, sOrd, ps, pt);
    combine<2><<<NR, 256, 0, stream>>>(ps, pt, Ws2, b2, (float*)0, (float*)0, r216);
    score_edges<<<(NE * 16 + 255) / 256, 256, 0, stream>>>(x16, r216, oi, ri, out);
}

// Round 14
// 220.767 us; speedup vs baseline: 1.1044x; 1.0697x over previous
//
#include <hip/hip_runtime.h>
#include <hip/hip_fp16.h>
#include <math.h>

#define NO 50000
#define NR 2000
#define NE 600000
#define D  128
#define NEG_SLOPE 0.2f
#define CAP 448    // per-rider edges cached in LDS (mean 300, max ~370)
#define SLOT 512   // fixed capacity per rider segment
#define NB 256     // sort chunk blocks
#define CH ((NE + NB - 1) / NB)   // 2344 edges per chunk

// ---------------------------------------------------------------------------
// K1: blockhist (blocks 0..NB-1)  ||  precompute_wv (block NB)
__global__ void prep_hist(const int* __restrict__ ri, int* __restrict__ blockHist,
                          const float* __restrict__ Ws1, const float* __restrict__ as1,
                          const float* __restrict__ Wd1, const float* __restrict__ ad1,
                          const float* __restrict__ Ws2, const float* __restrict__ as2,
                          const float* __restrict__ Wd2, const float* __restrict__ ad2,
                          float* __restrict__ wsv1, float* __restrict__ wdv1,
                          float* __restrict__ wsv2, float* __restrict__ wdv2) {
    __shared__ int h[NR];
    int t = threadIdx.x;
    if (blockIdx.x < NB) {
        int b = blockIdx.x;
        for (int i = t; i < NR; i += 256) h[i] = 0;
        __syncthreads();
        int lo = b * CH;
        int hi = lo + CH; if (hi > NE) hi = NE;
        for (int i = lo + t; i < hi; i += 256) atomicAdd(&h[ri[i]], 1);
        __syncthreads();
        for (int i = t; i < NR; i += 256) blockHist[(size_t)b * NR + i] = h[i];
    } else if (t < 128) {
        int k = t;
        float s1 = 0.f, d1 = 0.f, s2 = 0.f, d2 = 0.f;
        for (int j = 0; j < D; ++j) {
            s1 += Ws1[k * D + j] * as1[j];
            d1 += Wd1[k * D + j] * ad1[j];
            s2 += Ws2[k * D + j] * as2[j];
            d2 += Wd2[k * D + j] * ad2[j];
        }
        wsv1[k] = s1; wdv1[k] = d1; wsv2[k] = s2; wdv2[k] = d2;
    }
}

// ---------------------------------------------------------------------------
// K2: node_prep (orders then riders)  ||  rowscan (last 500 blocks)
__global__ void prep_scan(const float* __restrict__ x, const float* __restrict__ xr,
                          const float* __restrict__ wsv1, const float* __restrict__ wsv2,
                          const float* __restrict__ wdv1,
                          float* __restrict__ as1o, float* __restrict__ as2o,
                          float* __restrict__ ad1r, __half* __restrict__ x16,
                          int* __restrict__ blockHist, int* __restrict__ total) {
    int lane = threadIdx.x & 63;
    int b = blockIdx.x;
    if (b < NO / 4) {
        int row = b * 4 + (threadIdx.x >> 6);
        float2 xv = ((const float2*)(x + (size_t)row * D))[lane];
        float2 w1 = ((const float2*)wsv1)[lane];
        float2 w2 = ((const float2*)wsv2)[lane];
        float rx0 = fmaxf(xv.x, 0.f), rx1 = fmaxf(xv.y, 0.f);
        ((__half2*)(x16 + (size_t)row * D))[lane] = __floats2half2_rn(xv.x, xv.y);
        float a1 = xv.x * w1.x + xv.y * w1.y;
        float a2 = rx0 * w2.x + rx1 * w2.y;
        for (int off = 32; off; off >>= 1) {
            a1 += __shfl_down(a1, off);
            a2 += __shfl_down(a2, off);
        }
        if (lane == 0) { as1o[row] = a1; as2o[row] = a2; }
    } else if (b < NO / 4 + NR / 4) {
        int row = (b - NO / 4) * 4 + (threadIdx.x >> 6);
        float2 xv = ((const float2*)(xr + (size_t)row * D))[lane];
        float2 w1 = ((const float2*)wdv1)[lane];
        float a = xv.x * w1.x + xv.y * w1.y;
        for (int off = 32; off; off >>= 1) a += __shfl_down(a, off);
        if (lane == 0) ad1r[row] = a;
    } else {
        // rowscan: one wave per rider, shuffle-scan over 256 chunk counts
        int v = b - (NO / 4 + NR / 4);
        int r = v * 4 + (threadIdx.x >> 6);
        if (r >= NR) return;
        int b0 = lane * 4;
        int v0 = blockHist[(size_t)(b0 + 0) * NR + r];
        int v1 = blockHist[(size_t)(b0 + 1) * NR + r];
        int v2 = blockHist[(size_t)(b0 + 2) * NR + r];
        int v3 = blockHist[(size_t)(b0 + 3) * NR + r];
        int s = v0 + v1 + v2 + v3;
        int incl = s;
        for (int off = 1; off < 64; off <<= 1) {
            int u = __shfl_up(incl, off);
            if (lane >= off) incl += u;
        }
        int base = incl - s;
        blockHist[(size_t)(b0 + 0) * NR + r] = base;
        blockHist[(size_t)(b0 + 1) * NR + r] = base + v0;
        blockHist[(size_t)(b0 + 2) * NR + r] = base + v0 + v1;
        blockHist[(size_t)(b0 + 3) * NR + r] = base + v0 + v1 + v2;
        int tot = __shfl(incl, 63);
        if (lane == 0) total[r] = tot;
    }
}

// ---------------------------------------------------------------------------
__global__ void scatter_kernel(const int* __restrict__ oi, const int* __restrict__ ri,
                               const int* __restrict__ blockHist,
                               int* __restrict__ sOrd) {
    __shared__ int h[NR];
    int b = blockIdx.x, t = threadIdx.x;
    for (int i = t; i < NR; i += 256) h[i] = 0;
    __syncthreads();
    int lo = b * CH;
    int hi = lo + CH; if (hi > NE) hi = NE;
    for (int i = lo + t; i < hi; i += 256) {
        int r = ri[i];
        int rank = atomicAdd(&h[r], 1);
        int pos = r * SLOT + blockHist[(size_t)b * NR + r] + rank;
        sOrd[pos] = oi[i];
    }
}

// ---------------------------------------------------------------------------
// K4: merged layer-1 + layer-2 per rider.  ad2 passes through LDS (no global
// round-trip); sO cached once; layer-2 re-gather is L2-warm from layer-1.
__global__ void __launch_bounds__(256)
agg12(const __half* __restrict__ x16,
      const float* __restrict__ as1o, const float* __restrict__ as2o,
      const float* __restrict__ ad1r,
      const int* __restrict__ cnt, const int* __restrict__ sOrd,
      const float* __restrict__ W1, const float* __restrict__ b1,
      const float* __restrict__ wdv2,
      const float* __restrict__ W2, const float* __restrict__ b2,
      __half* __restrict__ r216) {
    __shared__ float eL[CAP];
    __shared__ int   sO[CAP];
    __shared__ float red[256];
    __shared__ float red8[256][9];   // +1 pad breaks stride-8 bank conflicts
    __shared__ float tl[D];
    int r = blockIdx.x, t = threadIdx.x;
    int base = r * SLOT, n = cnt[r];
    int grp = t >> 4, lh = t & 15;

    // ================= Layer 1 =================
    float ad1 = ad1r[r];
    float ls = 0.f;
    for (int i = t; i < n; i += 256) {
        int o = sOrd[base + i];
        float e = as1o[o] + ad1;
        e = (e > 0.f) ? e : NEG_SLOPE * e;
        float ex = __expf(e);
        if (i < CAP) { eL[i] = ex; sO[i] = o; }
        ls += ex;
    }
    red[t] = ls;
    __syncthreads();
    for (int off = 128; off; off >>= 1) {
        if (t < off) red[t] += red[t + off];
        __syncthreads();
    }
    float inv1 = 1.f / (red[0] + 1e-16f);
    __syncthreads();

    // gather 1: t1 = sum exp1 * x
    {
        float acc[8];
#pragma unroll
        for (int k = 0; k < 8; ++k) acc[k] = 0.f;
        if (n <= CAP) {
            int i = grp;
            for (; i + 16 < n; i += 32) {
                float a0 = eL[i], a1 = eL[i + 16];
                uint4 h0 = ((const uint4*)(x16 + (size_t)sO[i]      * D))[lh];
                uint4 h1 = ((const uint4*)(x16 + (size_t)sO[i + 16] * D))[lh];
                const __half2* p0 = (const __half2*)&h0;
                const __half2* p1 = (const __half2*)&h1;
#pragma unroll
                for (int q = 0; q < 4; ++q) {
                    float2 f0 = __half22float2(p0[q]);
                    float2 f1 = __half22float2(p1[q]);
                    acc[2 * q]     += a0 * f0.x + a1 * f1.x;
                    acc[2 * q + 1] += a0 * f0.y + a1 * f1.y;
                }
            }
            if (i < n) {
                float a0 = eL[i];
                uint4 h0 = ((const uint4*)(x16 + (size_t)sO[i] * D))[lh];
                const __half2* p0 = (const __half2*)&h0;
#pragma unroll
                for (int q = 0; q < 4; ++q) {
                    float2 f0 = __half22float2(p0[q]);
                    acc[2 * q]     += a0 * f0.x;
                    acc[2 * q + 1] += a0 * f0.y;
                }
            }
        } else {
            for (int i = grp; i < n; i += 16) {
                float a0; int o;
                if (i < CAP) { a0 = eL[i]; o = sO[i]; }
                else {
                    o = sOrd[base + i];
                    float e = as1o[o] + ad1;
                    e = (e > 0.f) ? e : NEG_SLOPE * e;
                    a0 = __expf(e);
                }
                uint4 h0 = ((const uint4*)(x16 + (size_t)o * D))[lh];
                const __half2* p0 = (const __half2*)&h0;
#pragma unroll
                for (int q = 0; q < 4; ++q) {
                    float2 f0 = __half22float2(p0[q]);
                    acc[2 * q]     += a0 * f0.x;
                    acc[2 * q + 1] += a0 * f0.y;
                }
            }
        }
#pragma unroll
        for (int k = 0; k < 8; ++k) red8[t][k] = acc[k];
    }
    __syncthreads();
    if (t < D) {
        int lh2 = t >> 3, k = t & 7;
        float s = 0.f;
        for (int g = 0; g < 16; ++g) s += red8[g * 16 + lh2][k];
        tl[t] = s * inv1;
    }
    __syncthreads();

    // GEMM1 -> ad2 (stays in LDS red[0])
    {
        int d = t & 127, h = t >> 7;
        float a = 0.f;
        for (int k = h * 64; k < h * 64 + 64; ++k) a += tl[k] * W1[k * D + d];
        red[t] = a;
        __syncthreads();
        if (t < 128) red[t] = fmaxf(red[t] + red[t + 128] + b1[t], 0.f) * wdv2[t];
        __syncthreads();
        for (int off = 64; off; off >>= 1) {
            if (t < off) red[t] += red[t + off];
            __syncthreads();
        }
    }
    float ad2 = red[0];
    __syncthreads();

    // ================= Layer 2 =================
    float ls2 = 0.f;
    for (int i = t; i < n; i += 256) {
        int o = (i < CAP) ? sO[i] : sOrd[base + i];
        float e = as2o[o] + ad2;
        e = (e > 0.f) ? e : NEG_SLOPE * e;
        float ex = __expf(e);
        if (i < CAP) eL[i] = ex;
        ls2 += ex;
    }
    red[t] = ls2;
    __syncthreads();
    for (int off = 128; off; off >>= 1) {
        if (t < off) red[t] += red[t + off];
        __syncthreads();
    }
    float inv2 = 1.f / (red[0] + 1e-16f);
    __syncthreads();

    // gather 2: t2 = sum exp2 * relu(x)   (rows L2-warm from gather 1)
    {
        float acc[8];
#pragma unroll
        for (int k = 0; k < 8; ++k) acc[k] = 0.f;
        if (n <= CAP) {
            int i = grp;
            for (; i + 16 < n; i += 32) {
                float a0 = eL[i], a1 = eL[i + 16];
                uint4 h0 = ((const uint4*)(x16 + (size_t)sO[i]      * D))[lh];
                uint4 h1 = ((const uint4*)(x16 + (size_t)sO[i + 16] * D))[lh];
                const __half2* p0 = (const __half2*)&h0;
                const __half2* p1 = (const __half2*)&h1;
#pragma unroll
                for (int q = 0; q < 4; ++q) {
                    float2 f0 = __half22float2(p0[q]);
                    float2 f1 = __half22float2(p1[q]);
                    acc[2 * q]     += a0 * fmaxf(f0.x, 0.f) + a1 * fmaxf(f1.x, 0.f);
                    acc[2 * q + 1] += a0 * fmaxf(f0.y, 0.f) + a1 * fmaxf(f1.y, 0.f);
                }
            }
            if (i < n) {
                float a0 = eL[i];
                uint4 h0 = ((const uint4*)(x16 + (size_t)sO[i] * D))[lh];
                const __half2* p0 = (const __half2*)&h0;
#pragma unroll
                for (int q = 0; q < 4; ++q) {
                    float2 f0 = __half22float2(p0[q]);
                    acc[2 * q]     += a0 * fmaxf(f0.x, 0.f);
                    acc[2 * q + 1] += a0 * fmaxf(f0.y, 0.f);
                }
            }
        } else {
            for (int i = grp; i < n; i += 16) {
                float a0; int o;
                if (i < CAP) { a0 = eL[i]; o = sO[i]; }
                else {
                    o = sOrd[base + i];
                    float e = as2o[o] + ad2;
                    e = (e > 0.f) ? e : NEG_SLOPE * e;
                    a0 = __expf(e);
                }
                uint4 h0 = ((const uint4*)(x16 + (size_t)o * D))[lh];
                const __half2* p0 = (const __half2*)&h0;
#pragma unroll
                for (int q = 0; q < 4; ++q) {
                    float2 f0 = __half22float2(p0[q]);
                    acc[2 * q]     += a0 * fmaxf(f0.x, 0.f);
                    acc[2 * q + 1] += a0 * fmaxf(f0.y, 0.f);
                }
            }
        }
#pragma unroll
        for (int k = 0; k < 8; ++k) red8[t][k] = acc[k];
    }
    __syncthreads();
    if (t < D) {
        int lh2 = t >> 3, k = t & 7;
        float s = 0.f;
        for (int g = 0; g < 16; ++g) s += red8[g * 16 + lh2][k];
        tl[t] = s * inv2;
    }
    __syncthreads();

    // GEMM2 -> r216
    {
        int d = t & 127, h = t >> 7;
        float a = 0.f;
        for (int k = h * 64; k < h * 64 + 64; ++k) a += tl[k] * W2[k * D + d];
        red[t] = a;
        __syncthreads();
        if (t < 128) r216[(size_t)r * D + t] = __float2half(red[t] + red[t + 128] + b2[t]);
    }
}

// ---------------------------------------------------------------------------
// K5: edge-parallel scoring: 16 lanes per edge, fp16 both sides, relu inline
__global__ void score_edges(const __half* __restrict__ x16, const __half* __restrict__ r216,
                            const int* __restrict__ oi, const int* __restrict__ ri,
                            float* __restrict__ out) {
    int gid = blockIdx.x * blockDim.x + threadIdx.x;
    int e  = gid >> 4;
    int lh = gid & 15;
    if (e >= NE) return;
    int o = oi[e], r = ri[e];
    uint4 hx = ((const uint4*)(x16  + (size_t)o * D))[lh];
    uint4 hr = ((const uint4*)(r216 + (size_t)r * D))[lh];
    float2 a0 = __half22float2(*(const __half2*)&hx.x);
    float2 a1 = __half22float2(*(const __half2*)&hx.y);
    float2 a2 = __half22float2(*(const __half2*)&hx.z);
    float2 a3 = __half22float2(*(const __half2*)&hx.w);
    float2 b0 = __half22float2(*(const __half2*)&hr.x);
    float2 b1 = __half22float2(*(const __half2*)&hr.y);
    float2 b2 = __half22float2(*(const __half2*)&hr.z);
    float2 b3 = __half22float2(*(const __half2*)&hr.w);
    float p = fmaxf(a0.x, 0.f) * b0.x + fmaxf(a0.y, 0.f) * b0.y +
              fmaxf(a1.x, 0.f) * b1.x + fmaxf(a1.y, 0.f) * b1.y +
              fmaxf(a2.x, 0.f) * b2.x + fmaxf(a2.y, 0.f) * b2.y +
              fmaxf(a3.x, 0.f) * b3.x + fmaxf(a3.y, 0.f) * b3.y;
    p += __shfl_xor(p, 8);
    p += __shfl_xor(p, 4);
    p += __shfl_xor(p, 2);
    p += __shfl_xor(p, 1);
    if (lh == 0) out[e] = 1.f / (1.f + __expf(-p));
}

// ---------------------------------------------------------------------------
extern "C" void kernel_launch(void* const* d_in, const int* in_sizes, int n_in,
                              void* d_out, int out_size, void* d_ws, size_t ws_size,
                              hipStream_t stream) {
    const float* x_order = (const float*)d_in[0];
    const float* x_rider = (const float*)d_in[1];
    const int*   oi      = (const int*)d_in[2];
    const int*   ri      = (const int*)d_in[3];
    const float* Ws1 = (const float*)d_in[4];
    const float* Wd1 = (const float*)d_in[5];
    const float* as1 = (const float*)d_in[6];
    const float* ad1 = (const float*)d_in[7];
    const float* b1  = (const float*)d_in[8];
    const float* Ws2 = (const float*)d_in[9];
    const float* Wd2 = (const float*)d_in[10];
    const float* as2 = (const float*)d_in[11];
    const float* ad2 = (const float*)d_in[12];
    const float* b2  = (const float*)d_in[13];
    float* out = (float*)d_out;

    // workspace carve-up (16B-aligned chunks)
    char* w = (char*)d_ws;
    float* wsv1 = (float*)w; w += 512;
    float* wdv1 = (float*)w; w += 512;
    float* wsv2 = (float*)w; w += 512;
    float* wdv2 = (float*)w; w += 512;
    float* as1o = (float*)w; w += (size_t)NO * 4;        // 200 KB
    float* as2o = (float*)w; w += (size_t)NO * 4;
    float* ad1r = (float*)w; w += (size_t)NR * 4;        // 8 KB
    int* total  = (int*)w;   w += (size_t)NR * 4;
    int* blockHist = (int*)w; w += (size_t)NB * NR * 4;  // 2 MB
    int* sOrd   = (int*)w;   w += (size_t)NR * SLOT * 4; // 4 MB
    __half* x16  = (__half*)w; w += (size_t)NO * D * 2;  // 12.8 MB
    __half* r216 = (__half*)w; w += (size_t)NR * D * 2;  // 512 KB

    prep_hist<<<NB + 1, 256, 0, stream>>>(ri, blockHist,
                                          Ws1, as1, Wd1, ad1, Ws2, as2, Wd2, ad2,
                                          wsv1, wdv1, wsv2, wdv2);
    prep_scan<<<NO / 4 + NR / 4 + 500, 256, 0, stream>>>(x_order, x_rider,
                                                         wsv1, wsv2, wdv1,
                                                         as1o, as2o, ad1r, x16,
                                                         blockHist, total);
    scatter_kernel<<<NB, 256, 0, stream>>>(oi, ri, blockHist, sOrd);
    agg12<<<NR, 256, 0, stream>>>(x16, as1o, as2o, ad1r, total, sOrd,
                                  Ws1, b1, wdv2, Ws2, b2, r216);
    score_edges<<<(NE * 16 + 255) / 256, 256, 0, stream>>>(x16, r216, oi, ri, out);
}